// Round 6
// baseline (349.103 us; speedup 1.0000x reference)
//
#include <hip/hip_runtime.h>
#include <hip/hip_bf16.h>
#include <math.h>

#define Mdim 2048
#define FD   128
#define SMEM_SZ 32768   // Bld 32 KB; mpool (24.8 KB) reuses it -> 4 blocks/CU

typedef __attribute__((ext_vector_type(8))) short short8;
typedef __attribute__((ext_vector_type(4))) float f32x4;

// ---------- pack float -> monotone u32 key | 11-bit global col index ----------
__device__ __forceinline__ unsigned pkey(float v, int n) {
    unsigned u = __float_as_uint(v);
    unsigned mk = u ^ ((unsigned)((int)u >> 31) | 0x80000000u);
    return (mk & 0xFFFFF800u) | (unsigned)n;
}

// branchless sorted-desc top-3 insert on packed keys
__device__ __forceinline__ void ins3p(unsigned k, unsigned t[3]) {
    bool g2 = k > t[2], g1 = k > t[1], g0 = k > t[0];
    t[2] = g1 ? t[1] : (g2 ? k : t[2]);
    t[1] = g0 ? t[0] : (g1 ? k : t[1]);
    t[0] = g0 ? k : t[0];
}

// sorted-desc top-8 insert with early-out (packed keys)
__device__ __forceinline__ void ins8p(unsigned k, unsigned bv[8]) {
    if (k <= bv[7]) return;
    #pragma unroll
    for (int s = 0; s < 8; ++s) {
        if (k > bv[s]) { unsigned o = bv[s]; bv[s] = k; k = o; }
    }
}

// ---------- Kernel 1: fp64 norms + normalized bf16 copy, chunk-swizzled ----------
// xnb row r, physical 16B-chunk p holds logical chunk j = p ^ (r & 15).
__global__ void prep_kernel(const float* __restrict__ x,
                            double* __restrict__ nrm_d,
                            unsigned short* __restrict__ xnb) {
    __shared__ unsigned short sb[4][128];
    int w = threadIdx.x >> 6, lane = threadIdx.x & 63;
    int row = blockIdx.x * 4 + w;
    const float* p = x + (size_t)row * FD;
    float v0 = p[lane], v1 = p[lane + 64];
    double d = (double)v0 * (double)v0 + (double)v1 * (double)v1;
    #pragma unroll
    for (int off = 32; off; off >>= 1) d += __shfl_down(d, off);
    d = __shfl(d, 0);
    double nrm = fmax(sqrt(d), 1e-12);
    if (lane == 0) nrm_d[row] = nrm;
    double inv = 1.0 / nrm;
    __hip_bfloat16 ha = __float2bfloat16((float)((double)v0 * inv));
    __hip_bfloat16 hb = __float2bfloat16((float)((double)v1 * inv));
    sb[w][lane]      = *reinterpret_cast<unsigned short*>(&ha);
    sb[w][lane + 64] = *reinterpret_cast<unsigned short*>(&hb);
    __syncthreads();
    if (lane < 16) {
        int j = lane ^ (row & 15);
        short8 v = *(const short8*)&sb[w][j * 8];
        *(short8*)(xnb + (size_t)row * FD + lane * 8) = v;
    }
}

// ---------- Kernel 2: MFMA GEMM over a column-half + packed top-8 pool ----------
// grid: 16 batches x 32 row-tiles x 2 column-halves = 1024 blocks (4/CU)
__launch_bounds__(256, 4)
__global__ void gemm_kernel(const unsigned short* __restrict__ xnb,
                            unsigned* __restrict__ pools,
                            float* __restrict__ out) {
    __shared__ __align__(16) char smem[SMEM_SZ];
    unsigned short* Bld = (unsigned short*)smem;  // [128 cols][128 k], source-swizzled

    int blk = blockIdx.x;
    int b   = blk >> 6;
    int rem = blk & 63;
    int rt  = rem >> 1;
    int hf  = rem & 1;
    int row0 = rt * 64;
    int colb = hf * 1024;
    const unsigned short* xb = xnb + (size_t)b * Mdim * FD;

    int tid  = threadIdx.x;
    int lane = tid & 63;
    int w    = tid >> 6;
    int wy   = w >> 1, wx = w & 1;     // wave tile: 32 rows x 64 cols
    int c    = lane & 15, q = lane >> 4;

    // A fragments (global chunks swizzled by row), held for whole kernel
    short8 afr[2][4];
    #pragma unroll
    for (int rs = 0; rs < 2; ++rs)
        #pragma unroll
        for (int s = 0; s < 4; ++s) {
            int row = row0 + wy*32 + rs*16 + c;
            int p = ((s << 2) + q) ^ (row & 15);
            afr[rs][s] = *(const short8*)(xb + (size_t)row * FD + p * 8);
        }

    // per-lane packed top-3 per owned row (8 rows/lane)
    unsigned tvp[8][3];
    #pragma unroll
    for (int i = 0; i < 8; ++i) { tvp[i][0] = 0; tvp[i][1] = 0; tvp[i][2] = 0; }

    float* zbase = out + (size_t)b * Mdim * Mdim
                 + (size_t)(row0 + (tid >> 5)) * Mdim + colb + (tid & 31) * 4;

    #pragma unroll 1
    for (int ch = 0; ch < 8; ++ch) {
        int col0 = colb + ch * 128;
        __syncthreads();   // drains previous iter's zero-stores + protects Bld
        {   // DMA stage: wave w covers cols [w*32, w*32+32)
            #pragma unroll
            for (int i = 0; i < 8; ++i) {
                const void* gp = xb + (size_t)(col0 + w*32 + i*4 + (lane >> 4)) * FD
                               + (lane & 15) * 8;
                void* lp = smem + ((w*32 + i*4) * 128) * sizeof(unsigned short);
                __builtin_amdgcn_global_load_lds(
                    (const __attribute__((address_space(1))) unsigned*)gp,
                    (__attribute__((address_space(3))) unsigned*)lp, 16, 0, 0);
            }
        }
        __syncthreads();

        // zero-write this chunk's output slice (in flight during MFMA/scan)
        {
            float4 z = make_float4(0.f, 0.f, 0.f, 0.f);
            #pragma unroll
            for (int t = 0; t < 8; ++t)
                *(float4*)(zbase + (size_t)t * 8 * Mdim) = z;
            zbase += 128;
        }

        f32x4 acc[2][4];
        #pragma unroll
        for (int rs = 0; rs < 2; ++rs)
            #pragma unroll
            for (int ct = 0; ct < 4; ++ct)
                acc[rs][ct] = (f32x4){0.f, 0.f, 0.f, 0.f};

        #pragma unroll
        for (int s = 0; s < 4; ++s)
            #pragma unroll
            for (int ct = 0; ct < 4; ++ct) {
                int p = ((s << 2) + q) ^ c;
                short8 bfr = *(const short8*)(Bld + (size_t)(wx*64 + ct*16 + c) * 128 + p * 8);
                acc[0][ct] = __builtin_amdgcn_mfma_f32_16x16x32_bf16(afr[0][s], bfr, acc[0][ct], 0, 0, 0);
                acc[1][ct] = __builtin_amdgcn_mfma_f32_16x16x32_bf16(afr[1][s], bfr, acc[1][ct], 0, 0, 0);
            }

        // scan on packed keys (diag competes; dropped at final select)
        int nbase = col0 + wx*64 + c;
        #pragma unroll
        for (int rs = 0; rs < 2; ++rs)
            #pragma unroll
            for (int i = 0; i < 4; ++i) {
                int rr = rs*4 + i;
                unsigned k0 = pkey(acc[rs][0][i], nbase);
                unsigned k1 = pkey(acc[rs][1][i], nbase + 16);
                unsigned k2 = pkey(acc[rs][2][i], nbase + 32);
                unsigned k3 = pkey(acc[rs][3][i], nbase + 48);
                unsigned mx = max(max(k0, k1), max(k2, k3));
                if (mx > tvp[rr][2]) {
                    ins3p(k0, tvp[rr]);
                    ins3p(k1, tvp[rr]);
                    ins3p(k2, tvp[rr]);
                    ins3p(k3, tvp[rr]);
                }
            }
    }

    // ---- merge: per-lane top-3 -> per-row top-8 -> global pool ----
    __syncthreads();
    unsigned* mpool = (unsigned*)smem;      // [64][97], reuses Bld
    {
        int slot = wx*16 + c;
        #pragma unroll
        for (int rs = 0; rs < 2; ++rs)
            #pragma unroll
            for (int i = 0; i < 4; ++i) {
                int rloc = wy*32 + rs*16 + q*4 + i;
                #pragma unroll
                for (int j = 0; j < 3; ++j)
                    mpool[rloc*97 + slot*3 + j] = tvp[rs*4 + i][j];
            }
    }
    __syncthreads();

    if (tid < 64) {
        unsigned bv[8];
        #pragma unroll
        for (int s = 0; s < 8; ++s) bv[s] = 0;
        for (int s2 = 0; s2 < 96; ++s2)
            ins8p(mpool[tid*97 + s2], bv);
        size_t rowg = (size_t)b * Mdim + row0 + tid;
        unsigned* pp = pools + rowg * 16 + hf * 8;
        #pragma unroll
        for (int s = 0; s < 8; ++s) pp[s] = bv[s];
    }
}

// ---------- Kernel 3: merge halves + fp64 refine + exact top-2 + atomic scatter ----------
// 32 rows per block, 8 threads per row. All writes additive on zeroed output.
__global__ void select_kernel(const float* __restrict__ x,
                              const double* __restrict__ nrm_d,
                              const unsigned* __restrict__ pools,
                              float* __restrict__ out) {
    __shared__ unsigned keys[32][8];
    __shared__ double   fval[32][9];
    int tid = threadIdx.x;
    int r = tid >> 3, s = tid & 7;
    int rowg = blockIdx.x * 32 + r;
    int b = rowg >> 11, m = rowg & (Mdim - 1);

    if (s == 0) {
        unsigned bv[8];
        #pragma unroll
        for (int i = 0; i < 8; ++i) bv[i] = 0;
        const unsigned* pp = pools + (size_t)rowg * 16;
        #pragma unroll
        for (int i = 0; i < 16; ++i) ins8p(pp[i], bv);
        #pragma unroll
        for (int i = 0; i < 8; ++i) keys[r][i] = bv[i];
    }
    __syncthreads();

    // fp64 refinement of candidate s for row m
    {
        int n = (int)(keys[r][s] & 2047u);
        const float* xf = x + (size_t)b * Mdim * FD;
        const double* nb = nrm_d + (size_t)b * Mdim;
        const f32x4* pm = (const f32x4*)(xf + (size_t)m * FD);
        const f32x4* pn = (const f32x4*)(xf + (size_t)n * FD);
        double a0 = 0.0, a1 = 0.0;
        #pragma unroll 4
        for (int k4 = 0; k4 < FD/4; k4 += 2) {
            f32x4 u0 = pm[k4],   vv0 = pn[k4];
            f32x4 u1 = pm[k4+1], vv1 = pn[k4+1];
            a0 = fma((double)u0[0], (double)vv0[0], a0);
            a0 = fma((double)u0[1], (double)vv0[1], a0);
            a0 = fma((double)u0[2], (double)vv0[2], a0);
            a0 = fma((double)u0[3], (double)vv0[3], a0);
            a1 = fma((double)u1[0], (double)vv1[0], a1);
            a1 = fma((double)u1[1], (double)vv1[1], a1);
            a1 = fma((double)u1[2], (double)vv1[2], a1);
            a1 = fma((double)u1[3], (double)vv1[3], a1);
        }
        fval[r][s] = (a0 + a1) / (nb[m] * nb[n]);
    }
    __syncthreads();

    if (s == 0) {
        double bv1 = -1e300, bv2 = -1e300; int bi1 = -1, bi2 = -1;
        #pragma unroll
        for (int cc = 0; cc < 8; ++cc) {
            double v = fval[r][cc];
            int    n = (int)(keys[r][cc] & 2047u);
            if (n == m) continue;           // drop self-similarity (diag)
            if (bi1 < 0 || v > bv1 || (v == bv1 && n < bi1)) {
                bv2 = bv1; bi2 = bi1; bv1 = v; bi1 = n;
            } else if (bi2 < 0 || v > bv2 || (v == bv2 && n < bi2)) {
                bv2 = v; bi2 = n;
            }
        }
        float* ob = out + (size_t)b * Mdim * Mdim;
        // reference top_k competes against the zeroed diagonal (value 0):
        // val1 always scatters; val2 only if it beats the diagonal zero.
        float h1 = (float)(0.5 * bv1);
        atomicAdd(ob + (size_t)m * Mdim + bi1, h1);
        atomicAdd(ob + (size_t)bi1 * Mdim + m, h1);
        if (bv2 > 0.0) {
            float h2 = (float)(0.5 * bv2);
            atomicAdd(ob + (size_t)m * Mdim + bi2, h2);
            atomicAdd(ob + (size_t)bi2 * Mdim + m, h2);
        }
    }
}

extern "C" void kernel_launch(void* const* d_in, const int* in_sizes, int n_in,
                              void* d_out, int out_size, void* d_ws, size_t ws_size,
                              hipStream_t stream) {
    const float* x = (const float*)d_in[0];
    float* out = (float*)d_out;
    int Bn = in_sizes[0] / (Mdim * FD);   // 16

    char* ws = (char*)d_ws;
    double*         nrm_d = (double*)ws;                          // 256 KB
    unsigned short* xnb   = (unsigned short*)(ws + 262144);       // 8 MB
    unsigned*       pools = (unsigned*)(ws + 262144 + 8388608);   // 2 MB

    prep_kernel<<<Bn * Mdim / 4, 256, 0, stream>>>(x, nrm_d, xnb);
    gemm_kernel<<<Bn * 64, 256, 0, stream>>>(xnb, pools, out);
    select_kernel<<<Bn * Mdim / 32, 256, 0, stream>>>(x, nrm_d, pools, out);
}